// Round 14
// baseline (398.433 us; speedup 1.0000x reference)
//
#include <hip/hip_runtime.h>
#include <hip/hip_fp16.h>
#include <stdint.h>

// ---------------------------------------------------------------------------
// Problem geometry (all compile-time):
//   x: (64, 48, 512, 2, 2) fp32. seq[s,n,f] = x[n, f>>2, 8*s, (f>>1)&1, f&1]
//   (only batch rows n<64 of the 512 matter downstream).
//   Layer1 BiGRU: in=192, H=256, 64 steps. Layer2 BiGRU: in=512, H=256.
//   Only final hiddens of layer2 used. dec_h = w_adj @ [hf,hb] + b_adj.
//   Decoder GRU (in=56, H=256) 6 steps, out = w_fc1@h + b_fc1 -> (64,6,56).
//
// SCAN LEDGER (r2-r13): compiler remats large resident sets (r2-r10);
// pure stream = port-bound 1.3-1.5us/step (r10); 64-block variants starve
// (r11); LDS-staging loses to h-broadcast port pressure in full-K shape
// (r12). Split-K 512thr hybrids: 92.8-96us (r9/r13) at 2 waves/SIMD,
// latency-limited (VALUBusy 26%). r14: 1024thr 4-way split-K -> 4 waves/
// SIMD, resident ask only 60 dwords/thread (5/8 chunks), stream 147KB/step.
// Also: adj fused into decoder (launch count 7 -> 6).
// ---------------------------------------------------------------------------

#define HD 256
#define G3 768
#define NSEQ 64
#define NSTEP 64

typedef _Float16 hvec2 __attribute__((ext_vector_type(2)));
typedef _Float16 f16x8 __attribute__((ext_vector_type(8)));
typedef float f32x4 __attribute__((ext_vector_type(4)));

__device__ __forceinline__ float sigmf(float x) {
    return 1.0f / (1.0f + __expf(-x));
}

#if __has_builtin(__builtin_amdgcn_fdot2)
__device__ __forceinline__ float fdot2u(uint32_t w, uint32_t h, float acc) {
    return __builtin_amdgcn_fdot2(__builtin_bit_cast(hvec2, w),
                                  __builtin_bit_cast(hvec2, h), acc, false);
}
#else
__device__ __forceinline__ float fdot2u(uint32_t w, uint32_t h, float acc) {
    const __half2 wv = __builtin_bit_cast(__half2, w);
    const __half2 hv = __builtin_bit_cast(__half2, h);
    acc += __half2float(wv.x) * __half2float(hv.x);
    acc += __half2float(wv.y) * __half2float(hv.y);
    return acc;
}
#endif

__device__ __forceinline__ uint32_t pkh(float a, float b) {
    uint32_t lo = __half_as_ushort(__float2half_rn(a));
    uint32_t hi = __half_as_ushort(__float2half_rn(b));
    return lo | (hi << 16);
}

#define L5(X) X(0) X(1) X(2) X(3) X(4)

// resident: 5 chunks per gate row x 3 rows = 15 uint4 = 60 dwords
#define LRES(i) \
    const uint4 wr##i = wbase[(i) * G3]; \
    const uint4 wz##i = wbase[(i) * G3 + 256]; \
    const uint4 wn##i = wbase[(i) * G3 + 512];

#define DRES(i) { \
    const uint4 hp = *(const uint4*)&hb[hoff + 4 * (i)]; \
    ar0 = fdot2u(wr##i.x, hp.x, ar0); ar1 = fdot2u(wr##i.y, hp.y, ar1); \
    ar0 = fdot2u(wr##i.z, hp.z, ar0); ar1 = fdot2u(wr##i.w, hp.w, ar1); \
    az0 = fdot2u(wz##i.x, hp.x, az0); az1 = fdot2u(wz##i.y, hp.y, az1); \
    az0 = fdot2u(wz##i.z, hp.z, az0); az1 = fdot2u(wz##i.w, hp.w, az1); \
    an0 = fdot2u(wn##i.x, hp.x, an0); an1 = fdot2u(wn##i.y, hp.y, an1); \
    an0 = fdot2u(wn##i.z, hp.z, an0); an1 = fdot2u(wn##i.w, hp.w, an1); }

// ---------------- merged weight/input prep (one launch) ----------------
// Block ranges:
//   [0,480)      pack Whh (5 tensors x 96 blocks)
//   [480,768)    wih1f/wih1b fp32->f16 (144 blocks each)
//   [768,1536)   wih2f/wih2b fp32->f16 (384 blocks each)
//   [1536,2272)  small transposes (736)
//   [2272,5344)  gather seq -> f16 (3072)
__global__ __launch_bounds__(256) void prep_all(
    const float* __restrict__ whh1f, const float* __restrict__ whh1b,
    const float* __restrict__ whh2f, const float* __restrict__ whh2b,
    const float* __restrict__ whhd,
    uint32_t* __restrict__ wt1f, uint32_t* __restrict__ wt1b,
    uint32_t* __restrict__ wt2f, uint32_t* __restrict__ wt2b,
    uint32_t* __restrict__ wtd,
    const float* __restrict__ wih1f, const float* __restrict__ wih1b,
    const float* __restrict__ wih2f, const float* __restrict__ wih2b,
    __half* __restrict__ wih1f_h, __half* __restrict__ wih1b_h,
    __half* __restrict__ wih2f_h, __half* __restrict__ wih2b_h,
    const float* __restrict__ wihd, const float* __restrict__ wadj,
    const float* __restrict__ wfc1,
    float* __restrict__ wihdT, float* __restrict__ wadjT,
    float* __restrict__ wfc1T,
    const float* __restrict__ x, __half* __restrict__ seqg)
{
    const int b   = blockIdx.x;
    const int tid = threadIdx.x;

    if (b < 480) {
        // Whh repack -> uint4[q*768 + j], q=0..31 holds k=8q..8q+7 of row j
        const int y = b / 96;
        const float* w; uint32_t* o;
        switch (y) {
            case 0: w = whh1f; o = wt1f; break;
            case 1: w = whh1b; o = wt1b; break;
            case 2: w = whh2f; o = wt2f; break;
            case 3: w = whh2b; o = wt2b; break;
            default: w = whhd; o = wtd; break;
        }
        const int idx = (b % 96) * 256 + tid;   // 24576
        const int j = idx >> 5, q = idx & 31;
        const float4 fa = *(const float4*)(w + j * HD + 8 * q);
        const float4 fb = *(const float4*)(w + j * HD + 8 * q + 4);
        uint4 r;
        r.x = pkh(fa.x, fa.y); r.y = pkh(fa.z, fa.w);
        r.z = pkh(fb.x, fb.y); r.w = pkh(fb.z, fb.w);
        ((uint4*)o)[q * G3 + j] = r;
    } else if (b < 1536) {
        const float* s; __half* d; int i4;
        if (b < 624)       { s = wih1f; d = wih1f_h; i4 = (b - 480) * 256 + tid; }
        else if (b < 768)  { s = wih1b; d = wih1b_h; i4 = (b - 624) * 256 + tid; }
        else if (b < 1152) { s = wih2f; d = wih2f_h; i4 = (b - 768) * 256 + tid; }
        else               { s = wih2b; d = wih2b_h; i4 = (b - 1152) * 256 + tid; }
        const float4 v = *(const float4*)(s + (size_t)i4 * 4);
        __half2 lo; lo.x = __float2half_rn(v.x); lo.y = __float2half_rn(v.y);
        __half2 hi; hi.x = __float2half_rn(v.z); hi.y = __float2half_rn(v.w);
        *(__half2*)(d + (size_t)i4 * 4)     = lo;
        *(__half2*)(d + (size_t)i4 * 4 + 2) = hi;
    } else if (b < 2272) {
        const int idx = (b - 1536) * 256 + tid;  // 188416
        if (idx < 43008) {
            int v = idx / G3, j = idx % G3;
            wihdT[idx] = wihd[j * 56 + v];
        } else if (idx < 43008 + 131072) {
            int i2 = idx - 43008;
            int f = i2 / HD, i = i2 % HD;
            wadjT[i2] = wadj[i * 512 + f];
        } else {
            int i3 = idx - 174080;
            int k = i3 / 56, v = i3 % 56;
            wfc1T[i3] = wfc1[v * HD + k];
        }
    } else {
        const int idx = (b - 2272) * 256 + tid;  // 786432
        const int f = idx % 192;
        const int m = idx / 192;
        const int n = m >> 6, s = m & 63;
        seqg[idx] = __float2half(
            x[n * 98304 + (f >> 2) * 2048 + s * 32 + (f & 3)]);
    }
}

// ---------------- f16 MFMA GEMM with bias ----------------
// C[m][j] = sum_k A[m][k]*B[j][k] + bias[j]; M=4096, N=768, K in {192,512}.
// grid=(64, 12, 2); block = 4 waves; wave w computes rows m0+16w..+16,
// cols n0..n0+63 as 4 accumulators. No LDS: operands are L2-resident.
// C/D layout (HW-verified): col=lane&15, row=(lane>>4)*4+reg.
__global__ __launch_bounds__(256) void gemm_mfma(
    const __half* __restrict__ A,
    const __half* __restrict__ B0, const __half* __restrict__ B1,
    const float* __restrict__ bias0, const float* __restrict__ bias1,
    float* __restrict__ C0, float* __restrict__ C1, int K)
{
    const __half* B    = blockIdx.z ? B1 : B0;
    const float*  bias = blockIdx.z ? bias1 : bias0;
    float*        C    = blockIdx.z ? C1 : C0;
    const int m0 = blockIdx.x * 64;
    const int n0 = blockIdx.y * 64;
    const int w  = threadIdx.x >> 6;
    const int l  = threadIdx.x & 63;
    const int lr = l & 15;
    const int lk = (l >> 4) * 8;

    const __half* arow = A + (size_t)(m0 + w * 16 + lr) * K + lk;
    const __half* brow = B + (size_t)(n0 + lr) * K + lk;

    f32x4 acc0 = {0.f, 0.f, 0.f, 0.f};
    f32x4 acc1 = acc0, acc2 = acc0, acc3 = acc0;

#pragma unroll 2
    for (int k0 = 0; k0 < K; k0 += 32) {
        const f16x8 a  = *(const f16x8*)(arow + k0);
        const f16x8 b0 = *(const f16x8*)(brow + k0);
        const f16x8 b1 = *(const f16x8*)(brow + 16 * K + k0);
        const f16x8 b2 = *(const f16x8*)(brow + 32 * K + k0);
        const f16x8 b3 = *(const f16x8*)(brow + 48 * K + k0);
        acc0 = __builtin_amdgcn_mfma_f32_16x16x32_f16(a, b0, acc0, 0, 0, 0);
        acc1 = __builtin_amdgcn_mfma_f32_16x16x32_f16(a, b1, acc1, 0, 0, 0);
        acc2 = __builtin_amdgcn_mfma_f32_16x16x32_f16(a, b2, acc2, 0, 0, 0);
        acc3 = __builtin_amdgcn_mfma_f32_16x16x32_f16(a, b3, acc3, 0, 0, 0);
    }

    const int crow = m0 + w * 16 + (l >> 4) * 4;
    const int ccol = n0 + lr;
    float* cp = C + (size_t)crow * G3 + ccol;
    const float bb0 = bias[ccol];
    const float bb1 = bias[ccol + 16];
    const float bb2 = bias[ccol + 32];
    const float bb3 = bias[ccol + 48];
#pragma unroll
    for (int j = 0; j < 4; ++j) {
        cp[(size_t)j * G3 +  0] = acc0[j] + bb0;
        cp[(size_t)j * G3 + 16] = acc1[j] + bb1;
        cp[(size_t)j * G3 + 32] = acc2[j] + bb2;
        cp[(size_t)j * G3 + 48] = acc3[j] + bb3;
    }
}

// ---------------- GRU scan: 1024 thr, 4-way split-K hybrid ----------------
// grid = 128 blocks: dir = blockIdx.x&1, n = blockIdx.x>>1.
// Thread (kq=t>>8, tr=t&255): gate rows {tr,256+tr,512+tr}, K-quarter kq
// (8 chunks of 8 k each). Chunks 0..4 resident (60 dwords — small ask,
// r9 precedent says the allocator holds this), 5..7 streamed (147KB/step).
// 16 waves/block = 4 waves/SIMD hides L2 latency (r13 had only 2).
// h-reads: 8 wave-uniform broadcast uint4/thread (free, m136).
// Quarters 1-3 publish partials; quarter 0 combines + gates; quarter 1
// prefetches gi during the gate phase.
__global__ __launch_bounds__(1024, 1) void gru_scan(
    const float* __restrict__ giF, const float* __restrict__ giB,
    const uint32_t* __restrict__ wTF, const uint32_t* __restrict__ wTB,
    const float* __restrict__ bhhF, const float* __restrict__ bhhB,
    __half* __restrict__ y1h, float* __restrict__ hfin)
{
    const int dir = blockIdx.x & 1;
    const int n   = blockIdx.x >> 1;
    const int t   = threadIdx.x;
    const int tr  = t & 255;
    const int kq  = t >> 8;          // K-quarter 0..3
    const int hoff = kq * 32;        // u32 offset into h buffer
    const float* gi  = dir ? giB : giF;
    const float* bhh = dir ? bhhB : bhhF;
    const uint4* wbase = (const uint4*)(dir ? wTB : wTF)
                       + (size_t)(kq * 8) * G3 + tr;

    __shared__ __align__(16) uint32_t h1u[2][HD / 2];   // h as f16x2, dbuf
    __shared__ float ph_r[3 * HD], ph_z[3 * HD], ph_n[3 * HD];
    __shared__ float gin[2][G3];                        // gi double buffer

    L5(LRES)
    const float bhr = bhh[tr], bhz = bhh[256 + tr], bhn = bhh[512 + tr];

    const float* gbase = gi + (size_t)n * NSTEP * G3;
    const int s0 = dir ? (NSTEP - 1) : 0;
    if (t < G3) gin[0][t] = gbase[s0 * G3 + t];

    float h_own = 0.0f;
    if (t < HD / 2) h1u[0][t] = 0u;
    __syncthreads();

    int s = s0;
    for (int step = 0; step < NSTEP; ++step) {
        const uint32_t* hb = h1u[step & 1];
        float ar0 = 0.f, ar1 = 0.f;
        float az0 = 0.f, az1 = 0.f;
        float an0 = 0.f, an1 = 0.f;
        L5(DRES)
#pragma unroll
        for (int i = 5; i < 8; ++i) {
            const uint4 sr = wbase[i * G3];
            const uint4 sz = wbase[i * G3 + 256];
            const uint4 sn = wbase[i * G3 + 512];
            const uint4 hp = *(const uint4*)&hb[hoff + 4 * i];
            ar0 = fdot2u(sr.x, hp.x, ar0); ar1 = fdot2u(sr.y, hp.y, ar1);
            ar0 = fdot2u(sr.z, hp.z, ar0); ar1 = fdot2u(sr.w, hp.w, ar1);
            az0 = fdot2u(sz.x, hp.x, az0); az1 = fdot2u(sz.y, hp.y, az1);
            az0 = fdot2u(sz.z, hp.z, az0); az1 = fdot2u(sz.w, hp.w, az1);
            an0 = fdot2u(sn.x, hp.x, an0); an1 = fdot2u(sn.y, hp.y, an1);
            an0 = fdot2u(sn.z, hp.z, an0); an1 = fdot2u(sn.w, hp.w, an1);
        }

        if (kq) {
            ph_r[(kq - 1) * HD + tr] = ar0 + ar1;
            ph_z[(kq - 1) * HD + tr] = az0 + az1;
            ph_n[(kq - 1) * HD + tr] = an0 + an1;
        }
        __syncthreads();
        const int s_nxt = dir ? (step < NSTEP - 1 ? NSTEP - 2 - step : 0)
                              : (step < NSTEP - 1 ? step + 1 : NSTEP - 1);
        if (kq == 0) {
            const float* gcur = gin[step & 1];
            const float ghr = (ar0 + ar1) + ph_r[tr] + ph_r[HD + tr]
                            + ph_r[2 * HD + tr] + bhr;
            const float ghz = (az0 + az1) + ph_z[tr] + ph_z[HD + tr]
                            + ph_z[2 * HD + tr] + bhz;
            const float ghn = (an0 + an1) + ph_n[tr] + ph_n[HD + tr]
                            + ph_n[2 * HD + tr] + bhn;
            const float r  = sigmf(gcur[tr] + ghr);
            const float z  = sigmf(gcur[256 + tr] + ghz);
            const float nn = tanhf(gcur[512 + tr] + r * ghn);
            const float hnew = (1.0f - z) * nn + z * h_own;
            h_own = hnew;
            const __half hh = __float2half(hnew);
            ((__half*)h1u[(step + 1) & 1])[tr] = hh;
            y1h[(size_t)(n * NSTEP + s) * 512 + dir * HD + tr] = hh;
        } else if (kq == 1) {
            float* gnxt = gin[(step + 1) & 1];
            gnxt[tr]       = gbase[s_nxt * G3 + tr];
            gnxt[256 + tr] = gbase[s_nxt * G3 + 256 + tr];
            gnxt[512 + tr] = gbase[s_nxt * G3 + 512 + tr];
        }
        s = s_nxt;
        __syncthreads();
    }
    if (kq == 0)
        hfin[(size_t)(dir * NSEQ + n) * HD + tr] = h_own;
}

// ---------------- decoder (adj fused): 64 blocks x 768 threads -------------
// Block n first computes dec_h[n] = w_adj @ [hf,hb] + b_adj (256 lanes,
// 512 MACs each), then runs the 6-step GRU + fc1 exactly as before.
__global__ __launch_bounds__(768, 3) void decoder_kernel(
    const float* __restrict__ hfin, const float* __restrict__ wadjT,
    const float* __restrict__ badj, const uint32_t* __restrict__ wTd,
    const float* __restrict__ wihdT, const float* __restrict__ bihd,
    const float* __restrict__ bhhd, const float* __restrict__ wfc1T,
    const float* __restrict__ bfc1, float* __restrict__ out)
{
    const int n = blockIdx.x, t = threadIdx.x;
    const uint4* wq = (const uint4*)wTd + t;

    __shared__ __align__(16) uint32_t h1u[2][HD / 2];
    __shared__ float comb[512];
    __shared__ float ghs[G3], gis[G3];
    __shared__ float hfp[HD];
    __shared__ float inp[56];
    __shared__ float pf1[448];

    const float bi = bihd[t], bh = bhhd[t];

    if (t < 512)
        comb[t] = (t < 256) ? hfin[(size_t)n * HD + t]
                            : hfin[(size_t)(NSEQ + n) * HD + (t - 256)];
    if (t < 56) inp[t] = 0.0f;
    __syncthreads();

    float h_own = 0.0f;
    if (t < HD) {
        float acc = badj[t];
#pragma unroll 8
        for (int f = 0; f < 512; ++f) acc += wadjT[f * HD + t] * comb[f];
        h_own = acc;
        ((__half*)h1u[0])[t] = __float2half(acc);
        hfp[t] = acc;
    }
    __syncthreads();

    for (int step = 0; step < 6; ++step) {
        const uint32_t* hb = h1u[step & 1];
        float a0 = 0.f, a1 = 0.f;
#pragma unroll 8
        for (int q = 0; q < 32; ++q) {
            const uint4 w = wq[q * G3];
            const uint4 hp = *(const uint4*)&hb[4 * q];
            a0 = fdot2u(w.x, hp.x, a0); a1 = fdot2u(w.y, hp.y, a1);
            a0 = fdot2u(w.z, hp.z, a0); a1 = fdot2u(w.w, hp.w, a1);
        }
        float ai = bi;
#pragma unroll 8
        for (int v = 0; v < 56; ++v) ai += wihdT[v * G3 + t] * inp[v];
        ghs[t] = a0 + a1 + bh;
        gis[t] = ai;
        __syncthreads();
        if (t < HD) {
            const float r  = sigmf(gis[t] + ghs[t]);
            const float z  = sigmf(gis[HD + t] + ghs[HD + t]);
            const float nn = tanhf(gis[2 * HD + t] + r * ghs[2 * HD + t]);
            const float hnew = (1.0f - z) * nn + z * h_own;
            h_own = hnew;
            ((__half*)h1u[(step + 1) & 1])[t] = __float2half(hnew);
            hfp[t] = hnew;
        }
        __syncthreads();
        if (t < 448) {
            const int v = t >> 3, g = t & 7;
            float o = 0.f;
#pragma unroll
            for (int k2 = 0; k2 < 32; ++k2)
                o += wfc1T[(g * 32 + k2) * 56 + v] * hfp[g * 32 + k2];
            pf1[t] = o;
        }
        __syncthreads();
        if (t < 56) {
            float o = bfc1[t];
#pragma unroll
            for (int g = 0; g < 8; ++g) o += pf1[t * 8 + g];
            out[(size_t)n * 336 + step * 56 + t] = o;
            inp[t] = o;
        }
        __syncthreads();
    }
}

// ---------------------------------------------------------------------------
extern "C" void kernel_launch(void* const* d_in, const int* in_sizes, int n_in,
                              void* d_out, int out_size, void* d_ws, size_t ws_size,
                              hipStream_t stream)
{
    const float* x      = (const float*)d_in[0];
    const float* wih1f  = (const float*)d_in[1];
    const float* whh1f  = (const float*)d_in[2];
    const float* bih1f  = (const float*)d_in[3];
    const float* bhh1f  = (const float*)d_in[4];
    const float* wih1b  = (const float*)d_in[5];
    const float* whh1b  = (const float*)d_in[6];
    const float* bih1b  = (const float*)d_in[7];
    const float* bhh1b  = (const float*)d_in[8];
    const float* wih2f  = (const float*)d_in[9];
    const float* whh2f  = (const float*)d_in[10];
    const float* bih2f  = (const float*)d_in[11];
    const float* bhh2f  = (const float*)d_in[12];
    const float* wih2b  = (const float*)d_in[13];
    const float* whh2b  = (const float*)d_in[14];
    const float* bih2b  = (const float*)d_in[15];
    const float* bhh2b  = (const float*)d_in[16];
    const float* wihd   = (const float*)d_in[17];
    const float* whhd   = (const float*)d_in[18];
    const float* bihd   = (const float*)d_in[19];
    const float* bhhd   = (const float*)d_in[20];
    const float* wfc1   = (const float*)d_in[21];
    const float* bfc1   = (const float*)d_in[22];
    const float* wadj   = (const float*)d_in[23];
    const float* badj   = (const float*)d_in[24];

    float* ws = (float*)d_ws;
    __half*   seqg_h  = (__half*)(ws + 0);           // 786432 f16
    float*    gi_f    = ws + 393216;                 // 3145728
    float*    gi_b    = ws + 3538944;                // 3145728
    __half*   y1h     = (__half*)(ws + 6684672);     // 2097152 f16
    float*    hfin    = ws + 7733248;                // 32768
    uint32_t* wt1f    = (uint32_t*)(ws + 7782400);   // 98304 each
    uint32_t* wt1b    = (uint32_t*)(ws + 7880704);
    uint32_t* wt2f    = (uint32_t*)(ws + 7979008);
    uint32_t* wt2b    = (uint32_t*)(ws + 8077312);
    uint32_t* wtd     = (uint32_t*)(ws + 8175616);
    __half*   wih1f_h = (__half*)(ws + 8273920);     // 147456 f16
    __half*   wih1b_h = (__half*)(ws + 8347648);
    __half*   wih2f_h = (__half*)(ws + 8421376);     // 393216 f16
    __half*   wih2b_h = (__half*)(ws + 8617984);
    float*    wihdT   = ws + 8814592;                // 43008
    float*    wadjT   = ws + 8857600;                // 131072
    float*    wfc1T   = ws + 8988672;                // 14336

    prep_all<<<5344, 256, 0, stream>>>(
        whh1f, whh1b, whh2f, whh2b, whhd,
        wt1f, wt1b, wt2f, wt2b, wtd,
        wih1f, wih1b, wih2f, wih2b,
        wih1f_h, wih1b_h, wih2f_h, wih2b_h,
        wihd, wadj, wfc1, wihdT, wadjT, wfc1T,
        x, seqg_h);

    // layer 1
    gemm_mfma<<<dim3(64, 12, 2), 256, 0, stream>>>(
        seqg_h, wih1f_h, wih1b_h, bih1f, bih1b, gi_f, gi_b, 192);
    gru_scan<<<128, 1024, 0, stream>>>(
        gi_f, gi_b, wt1f, wt1b, bhh1f, bhh1b, y1h, hfin);

    // layer 2 (gi buffers reused; scan2's y1h writes are dead but harmless)
    gemm_mfma<<<dim3(64, 12, 2), 256, 0, stream>>>(
        y1h, wih2f_h, wih2b_h, bih2f, bih2b, gi_f, gi_b, 512);
    gru_scan<<<128, 1024, 0, stream>>>(
        gi_f, gi_b, wt2f, wt2b, bhh2f, bhh2b, y1h, hfin);

    // decoder head (adj fused)
    decoder_kernel<<<64, 768, 0, stream>>>(
        hfin, wadjT, badj, wtd, wihdT, bihd, bhhd, wfc1T, bfc1,
        (float*)d_out);
}

// Round 15
// 345.645 us; speedup vs baseline: 1.1527x; 1.1527x over previous
//
#include <hip/hip_runtime.h>
#include <hip/hip_fp16.h>
#include <stdint.h>

// ---------------------------------------------------------------------------
// Problem geometry (all compile-time):
//   x: (64, 48, 512, 2, 2) fp32. seq[s,n,f] = x[n, f>>2, 8*s, (f>>1)&1, f&1]
//   (only batch rows n<64 of the 512 matter downstream).
//   Layer1 BiGRU: in=192, H=256, 64 steps. Layer2 BiGRU: in=512, H=256.
//   Only final hiddens of layer2 used. dec_h = w_adj @ [hf,hb] + b_adj.
//   Decoder GRU (in=56, H=256) 6 steps, out = w_fc1@h + b_fc1 -> (64,6,56).
//
// SCAN LEDGER — FINAL (r2-r14):
//   * compiler remats any large resident weight set (pins/AGPR-asm/alias
//     tricks all failed; r2-r10);
//   * full-stream floor = L2 AGGREGATE roofline: 50MB/step / 14.2KB/cyc
//     = 1.48us/step (r10=1.5, r14=1.8 with partial overhead);
//   * <128 blocks latency-starves (r11: 5.3us/step);
//   * LDS weight delivery can't beat L2: ds_read_b128 ~12cyc => 85B/cyc/CU
//     ~= L2 port 111B/cyc (r12 measured 1.9us/step);
//   * int8/fp8 weights fail the 1.117e-2 absmax budget (est 1-3e-2).
//   BEST: r9 shape — split-K (512,1), L16 resident-attempt: allocator
//   voluntarily holds ~72 dwords (VGPR 116), streams the rest: 92.8us.
//   This round: restore r9 scan exactly; K-templated MFMA gemm; keep
//   merged prep_all (r11, ~-100us) and fused adj+decoder (r14).
// ---------------------------------------------------------------------------

#define HD 256
#define G3 768
#define NSEQ 64
#define NSTEP 64

typedef _Float16 hvec2 __attribute__((ext_vector_type(2)));
typedef _Float16 f16x8 __attribute__((ext_vector_type(8)));
typedef float f32x4 __attribute__((ext_vector_type(4)));

__device__ __forceinline__ float sigmf(float x) {
    return 1.0f / (1.0f + __expf(-x));
}

#if __has_builtin(__builtin_amdgcn_fdot2)
__device__ __forceinline__ float fdot2u(uint32_t w, uint32_t h, float acc) {
    return __builtin_amdgcn_fdot2(__builtin_bit_cast(hvec2, w),
                                  __builtin_bit_cast(hvec2, h), acc, false);
}
#else
__device__ __forceinline__ float fdot2u(uint32_t w, uint32_t h, float acc) {
    const __half2 wv = __builtin_bit_cast(__half2, w);
    const __half2 hv = __builtin_bit_cast(__half2, h);
    acc += __half2float(wv.x) * __half2float(hv.x);
    acc += __half2float(wv.y) * __half2float(hv.y);
    return acc;
}
#endif

__device__ __forceinline__ uint32_t pkh(float a, float b) {
    uint32_t lo = __half_as_ushort(__float2half_rn(a));
    uint32_t hi = __half_as_ushort(__float2half_rn(b));
    return lo | (hi << 16);
}

#define L16(X) X(0) X(1) X(2) X(3) X(4) X(5) X(6) X(7) \
  X(8) X(9) X(10) X(11) X(12) X(13) X(14) X(15)

// resident-attempt: 16 chunks per gate row x 3 rows = 48 uint4 = 192 dwords.
// The allocator keeps ~6 chunks (72 dwords, VGPR 116) and streams the rest —
// measured BEST at 92.8us/scan (r9). Do not "fix"; every alternative lost.
#define LRES(i) \
    const uint4 wr##i = wbase[(i) * G3]; \
    const uint4 wz##i = wbase[(i) * G3 + 256]; \
    const uint4 wn##i = wbase[(i) * G3 + 512];

#define DRES(i) { \
    const uint4 hp = *(const uint4*)&hb[hoff + 4 * (i)]; \
    ar0 = fdot2u(wr##i.x, hp.x, ar0); ar1 = fdot2u(wr##i.y, hp.y, ar1); \
    ar0 = fdot2u(wr##i.z, hp.z, ar0); ar1 = fdot2u(wr##i.w, hp.w, ar1); \
    az0 = fdot2u(wz##i.x, hp.x, az0); az1 = fdot2u(wz##i.y, hp.y, az1); \
    az0 = fdot2u(wz##i.z, hp.z, az0); az1 = fdot2u(wz##i.w, hp.w, az1); \
    an0 = fdot2u(wn##i.x, hp.x, an0); an1 = fdot2u(wn##i.y, hp.y, an1); \
    an0 = fdot2u(wn##i.z, hp.z, an0); an1 = fdot2u(wn##i.w, hp.w, an1); }

// ---------------- merged weight/input prep (one launch) ----------------
// Block ranges:
//   [0,480)      pack Whh (5 tensors x 96 blocks)
//   [480,768)    wih1f/wih1b fp32->f16 (144 blocks each)
//   [768,1536)   wih2f/wih2b fp32->f16 (384 blocks each)
//   [1536,2272)  small transposes (736)
//   [2272,5344)  gather seq -> f16 (3072)
__global__ __launch_bounds__(256) void prep_all(
    const float* __restrict__ whh1f, const float* __restrict__ whh1b,
    const float* __restrict__ whh2f, const float* __restrict__ whh2b,
    const float* __restrict__ whhd,
    uint32_t* __restrict__ wt1f, uint32_t* __restrict__ wt1b,
    uint32_t* __restrict__ wt2f, uint32_t* __restrict__ wt2b,
    uint32_t* __restrict__ wtd,
    const float* __restrict__ wih1f, const float* __restrict__ wih1b,
    const float* __restrict__ wih2f, const float* __restrict__ wih2b,
    __half* __restrict__ wih1f_h, __half* __restrict__ wih1b_h,
    __half* __restrict__ wih2f_h, __half* __restrict__ wih2b_h,
    const float* __restrict__ wihd, const float* __restrict__ wadj,
    const float* __restrict__ wfc1,
    float* __restrict__ wihdT, float* __restrict__ wadjT,
    float* __restrict__ wfc1T,
    const float* __restrict__ x, __half* __restrict__ seqg)
{
    const int b   = blockIdx.x;
    const int tid = threadIdx.x;

    if (b < 480) {
        // Whh repack -> uint4[q*768 + j], q=0..31 holds k=8q..8q+7 of row j
        const int y = b / 96;
        const float* w; uint32_t* o;
        switch (y) {
            case 0: w = whh1f; o = wt1f; break;
            case 1: w = whh1b; o = wt1b; break;
            case 2: w = whh2f; o = wt2f; break;
            case 3: w = whh2b; o = wt2b; break;
            default: w = whhd; o = wtd; break;
        }
        const int idx = (b % 96) * 256 + tid;   // 24576
        const int j = idx >> 5, q = idx & 31;
        const float4 fa = *(const float4*)(w + j * HD + 8 * q);
        const float4 fb = *(const float4*)(w + j * HD + 8 * q + 4);
        uint4 r;
        r.x = pkh(fa.x, fa.y); r.y = pkh(fa.z, fa.w);
        r.z = pkh(fb.x, fb.y); r.w = pkh(fb.z, fb.w);
        ((uint4*)o)[q * G3 + j] = r;
    } else if (b < 1536) {
        const float* s; __half* d; int i4;
        if (b < 624)       { s = wih1f; d = wih1f_h; i4 = (b - 480) * 256 + tid; }
        else if (b < 768)  { s = wih1b; d = wih1b_h; i4 = (b - 624) * 256 + tid; }
        else if (b < 1152) { s = wih2f; d = wih2f_h; i4 = (b - 768) * 256 + tid; }
        else               { s = wih2b; d = wih2b_h; i4 = (b - 1152) * 256 + tid; }
        const float4 v = *(const float4*)(s + (size_t)i4 * 4);
        __half2 lo; lo.x = __float2half_rn(v.x); lo.y = __float2half_rn(v.y);
        __half2 hi; hi.x = __float2half_rn(v.z); hi.y = __float2half_rn(v.w);
        *(__half2*)(d + (size_t)i4 * 4)     = lo;
        *(__half2*)(d + (size_t)i4 * 4 + 2) = hi;
    } else if (b < 2272) {
        const int idx = (b - 1536) * 256 + tid;  // 188416
        if (idx < 43008) {
            int v = idx / G3, j = idx % G3;
            wihdT[idx] = wihd[j * 56 + v];
        } else if (idx < 43008 + 131072) {
            int i2 = idx - 43008;
            int f = i2 / HD, i = i2 % HD;
            wadjT[i2] = wadj[i * 512 + f];
        } else {
            int i3 = idx - 174080;
            int k = i3 / 56, v = i3 % 56;
            wfc1T[i3] = wfc1[v * HD + k];
        }
    } else {
        const int idx = (b - 2272) * 256 + tid;  // 786432
        const int f = idx % 192;
        const int m = idx / 192;
        const int n = m >> 6, s = m & 63;
        seqg[idx] = __float2half(
            x[n * 98304 + (f >> 2) * 2048 + s * 32 + (f & 3)]);
    }
}

// ---------------- f16 MFMA GEMM with bias (K compile-time) ----------------
// C[m][j] = sum_k A[m][k]*B[j][k] + bias[j]; M=4096, N=768, K in {192,512}.
// grid=(64, 12, 2); block = 4 waves; wave w computes rows m0+16w..+16,
// cols n0..n0+63 as 4 accumulators. No LDS: operands are L2-resident.
// C/D layout (HW-verified): col=lane&15, row=(lane>>4)*4+reg.
template <int K>
__global__ __launch_bounds__(256) void gemm_mfma(
    const __half* __restrict__ A,
    const __half* __restrict__ B0, const __half* __restrict__ B1,
    const float* __restrict__ bias0, const float* __restrict__ bias1,
    float* __restrict__ C0, float* __restrict__ C1)
{
    const __half* B    = blockIdx.z ? B1 : B0;
    const float*  bias = blockIdx.z ? bias1 : bias0;
    float*        C    = blockIdx.z ? C1 : C0;
    const int m0 = blockIdx.x * 64;
    const int n0 = blockIdx.y * 64;
    const int w  = threadIdx.x >> 6;
    const int l  = threadIdx.x & 63;
    const int lr = l & 15;
    const int lk = (l >> 4) * 8;

    const __half* arow = A + (size_t)(m0 + w * 16 + lr) * K + lk;
    const __half* brow = B + (size_t)(n0 + lr) * K + lk;

    f32x4 acc0 = {0.f, 0.f, 0.f, 0.f};
    f32x4 acc1 = acc0, acc2 = acc0, acc3 = acc0;

#pragma unroll
    for (int k0 = 0; k0 < K; k0 += 32) {
        const f16x8 a  = *(const f16x8*)(arow + k0);
        const f16x8 b0 = *(const f16x8*)(brow + k0);
        const f16x8 b1 = *(const f16x8*)(brow + 16 * K + k0);
        const f16x8 b2 = *(const f16x8*)(brow + 32 * K + k0);
        const f16x8 b3 = *(const f16x8*)(brow + 48 * K + k0);
        acc0 = __builtin_amdgcn_mfma_f32_16x16x32_f16(a, b0, acc0, 0, 0, 0);
        acc1 = __builtin_amdgcn_mfma_f32_16x16x32_f16(a, b1, acc1, 0, 0, 0);
        acc2 = __builtin_amdgcn_mfma_f32_16x16x32_f16(a, b2, acc2, 0, 0, 0);
        acc3 = __builtin_amdgcn_mfma_f32_16x16x32_f16(a, b3, acc3, 0, 0, 0);
    }

    const int crow = m0 + w * 16 + (l >> 4) * 4;
    const int ccol = n0 + lr;
    float* cp = C + (size_t)crow * G3 + ccol;
    const float bb0 = bias[ccol];
    const float bb1 = bias[ccol + 16];
    const float bb2 = bias[ccol + 32];
    const float bb3 = bias[ccol + 48];
#pragma unroll
    for (int j = 0; j < 4; ++j) {
        cp[(size_t)j * G3 +  0] = acc0[j] + bb0;
        cp[(size_t)j * G3 + 16] = acc1[j] + bb1;
        cp[(size_t)j * G3 + 32] = acc2[j] + bb2;
        cp[(size_t)j * G3 + 48] = acc3[j] + bb3;
    }
}

// ---------------- GRU scan (r9 shape — best measured, 92.8us) --------------
// grid = 128 blocks: dir = blockIdx.x&1, n = blockIdx.x>>1.
// 512 threads: thread (kh=t>>8, tr=t&255) owns gate rows {tr,256+tr,512+tr}
// for K-half kh. All 16 chunks declared resident; allocator keeps ~6 and
// streams the rest (VGPR 116) — measured optimum. kh==1 half prefetches
// next step's gi into LDS during the gate phase. h dbuf f16x2 in LDS.
__global__ __launch_bounds__(512, 1) void gru_scan(
    const float* __restrict__ giF, const float* __restrict__ giB,
    const uint32_t* __restrict__ wTF, const uint32_t* __restrict__ wTB,
    const float* __restrict__ bhhF, const float* __restrict__ bhhB,
    __half* __restrict__ y1h, float* __restrict__ hfin)
{
    const int dir = blockIdx.x & 1;
    const int n   = blockIdx.x >> 1;
    const int t   = threadIdx.x;
    const int tr  = t & 255;
    const int kh  = t >> 8;
    const int hoff = kh * 64;        // u32 offset into h buffer
    const float* gi  = dir ? giB : giF;
    const float* bhh = dir ? bhhB : bhhF;
    const uint4* wbase = (const uint4*)(dir ? wTB : wTF)
                       + (size_t)(kh * 16) * G3 + tr;

    __shared__ __align__(16) uint32_t h1u[2][HD / 2];  // h as f16x2, dbuf
    __shared__ float ph_r[HD], ph_z[HD], ph_n[HD];     // upper-half partials
    __shared__ float gin[2][G3];                       // gi double buffer

    L16(LRES)
    const float bhr = bhh[tr], bhz = bhh[256 + tr], bhn = bhh[512 + tr];

    const float* gbase = gi + (size_t)n * NSTEP * G3;
    const int s0 = dir ? (NSTEP - 1) : 0;
#pragma unroll
    for (int i = t; i < G3; i += 512) gin[0][i] = gbase[s0 * G3 + i];

    float h_own = 0.0f;
    if (t < HD / 2) h1u[0][t] = 0u;
    __syncthreads();

    int s = s0;
    for (int step = 0; step < NSTEP; ++step) {
        const uint32_t* hb = h1u[step & 1];
        float ar0 = 0.f, ar1 = 0.f;
        float az0 = 0.f, az1 = 0.f;
        float an0 = 0.f, an1 = 0.f;
        L16(DRES)

        if (kh) {
            ph_r[tr] = ar0 + ar1;
            ph_z[tr] = az0 + az1;
            ph_n[tr] = an0 + an1;
        }
        __syncthreads();
        const int s_nxt = dir ? (step < NSTEP - 1 ? NSTEP - 2 - step : 0)
                              : (step < NSTEP - 1 ? step + 1 : NSTEP - 1);
        if (kh == 0) {
            const float* gcur = gin[step & 1];
            const float ghr = (ar0 + ar1) + ph_r[tr] + bhr;
            const float ghz = (az0 + az1) + ph_z[tr] + bhz;
            const float ghn = (an0 + an1) + ph_n[tr] + bhn;
            const float r  = sigmf(gcur[tr] + ghr);
            const float z  = sigmf(gcur[256 + tr] + ghz);
            const float nn = tanhf(gcur[512 + tr] + r * ghn);
            const float hnew = (1.0f - z) * nn + z * h_own;
            h_own = hnew;
            const __half hh = __float2half(hnew);
            ((__half*)h1u[(step + 1) & 1])[tr] = hh;
            y1h[(size_t)(n * NSTEP + s) * 512 + dir * HD + tr] = hh;
        } else {
            float* gnxt = gin[(step + 1) & 1];
            gnxt[tr]       = gbase[s_nxt * G3 + tr];
            gnxt[256 + tr] = gbase[s_nxt * G3 + 256 + tr];
            gnxt[512 + tr] = gbase[s_nxt * G3 + 512 + tr];
        }
        s = s_nxt;
        __syncthreads();
    }
    if (kh == 0)
        hfin[(size_t)(dir * NSEQ + n) * HD + tr] = h_own;
}

// ---------------- decoder (adj fused): 64 blocks x 768 threads -------------
// Block n computes dec_h[n] = w_adj @ [hf,hb] + b_adj, then the 6-step GRU
// (streamed weights — no residency fight) + fc1 with 8-way split-K.
__global__ __launch_bounds__(768, 3) void decoder_kernel(
    const float* __restrict__ hfin, const float* __restrict__ wadjT,
    const float* __restrict__ badj, const uint32_t* __restrict__ wTd,
    const float* __restrict__ wihdT, const float* __restrict__ bihd,
    const float* __restrict__ bhhd, const float* __restrict__ wfc1T,
    const float* __restrict__ bfc1, float* __restrict__ out)
{
    const int n = blockIdx.x, t = threadIdx.x;
    const uint4* wq = (const uint4*)wTd + t;

    __shared__ __align__(16) uint32_t h1u[2][HD / 2];
    __shared__ float comb[512];
    __shared__ float ghs[G3], gis[G3];
    __shared__ float hfp[HD];
    __shared__ float inp[56];
    __shared__ float pf1[448];

    const float bi = bihd[t], bh = bhhd[t];

    if (t < 512)
        comb[t] = (t < 256) ? hfin[(size_t)n * HD + t]
                            : hfin[(size_t)(NSEQ + n) * HD + (t - 256)];
    if (t < 56) inp[t] = 0.0f;
    __syncthreads();

    float h_own = 0.0f;
    if (t < HD) {
        float acc = badj[t];
#pragma unroll 8
        for (int f = 0; f < 512; ++f) acc += wadjT[f * HD + t] * comb[f];
        h_own = acc;
        ((__half*)h1u[0])[t] = __float2half(acc);
        hfp[t] = acc;
    }
    __syncthreads();

    for (int step = 0; step < 6; ++step) {
        const uint32_t* hb = h1u[step & 1];
        float a0 = 0.f, a1 = 0.f;
#pragma unroll 8
        for (int q = 0; q < 32; ++q) {
            const uint4 w = wq[q * G3];
            const uint4 hp = *(const uint4*)&hb[4 * q];
            a0 = fdot2u(w.x, hp.x, a0); a1 = fdot2u(w.y, hp.y, a1);
            a0 = fdot2u(w.z, hp.z, a0); a1 = fdot2u(w.w, hp.w, a1);
        }
        float ai = bi;
#pragma unroll 8
        for (int v = 0; v < 56; ++v) ai += wihdT[v * G3 + t] * inp[v];
        ghs[t] = a0 + a1 + bh;
        gis[t] = ai;
        __syncthreads();
        if (t < HD) {
            const float r  = sigmf(gis[t] + ghs[t]);
            const float z  = sigmf(gis[HD + t] + ghs[HD + t]);
            const float nn = tanhf(gis[2 * HD + t] + r * ghs[2 * HD + t]);
            const float hnew = (1.0f - z) * nn + z * h_own;
            h_own = hnew;
            ((__half*)h1u[(step + 1) & 1])[t] = __float2half(hnew);
            hfp[t] = hnew;
        }
        __syncthreads();
        if (t < 448) {
            const int v = t >> 3, g = t & 7;
            float o = 0.f;
#pragma unroll
            for (int k2 = 0; k2 < 32; ++k2)
                o += wfc1T[(g * 32 + k2) * 56 + v] * hfp[g * 32 + k2];
            pf1[t] = o;
        }
        __syncthreads();
        if (t < 56) {
            float o = bfc1[t];
#pragma unroll
            for (int g = 0; g < 8; ++g) o += pf1[t * 8 + g];
            out[(size_t)n * 336 + step * 56 + t] = o;
            inp[t] = o;
        }
        __syncthreads();
    }
}

// ---------------------------------------------------------------------------
extern "C" void kernel_launch(void* const* d_in, const int* in_sizes, int n_in,
                              void* d_out, int out_size, void* d_ws, size_t ws_size,
                              hipStream_t stream)
{
    const float* x      = (const float*)d_in[0];
    const float* wih1f  = (const float*)d_in[1];
    const float* whh1f  = (const float*)d_in[2];
    const float* bih1f  = (const float*)d_in[3];
    const float* bhh1f  = (const float*)d_in[4];
    const float* wih1b  = (const float*)d_in[5];
    const float* whh1b  = (const float*)d_in[6];
    const float* bih1b  = (const float*)d_in[7];
    const float* bhh1b  = (const float*)d_in[8];
    const float* wih2f  = (const float*)d_in[9];
    const float* whh2f  = (const float*)d_in[10];
    const float* bih2f  = (const float*)d_in[11];
    const float* bhh2f  = (const float*)d_in[12];
    const float* wih2b  = (const float*)d_in[13];
    const float* whh2b  = (const float*)d_in[14];
    const float* bih2b  = (const float*)d_in[15];
    const float* bhh2b  = (const float*)d_in[16];
    const float* wihd   = (const float*)d_in[17];
    const float* whhd   = (const float*)d_in[18];
    const float* bihd   = (const float*)d_in[19];
    const float* bhhd   = (const float*)d_in[20];
    const float* wfc1   = (const float*)d_in[21];
    const float* bfc1   = (const float*)d_in[22];
    const float* wadj   = (const float*)d_in[23];
    const float* badj   = (const float*)d_in[24];

    float* ws = (float*)d_ws;
    __half*   seqg_h  = (__half*)(ws + 0);           // 786432 f16
    float*    gi_f    = ws + 393216;                 // 3145728
    float*    gi_b    = ws + 3538944;                // 3145728
    __half*   y1h     = (__half*)(ws + 6684672);     // 2097152 f16
    float*    hfin    = ws + 7733248;                // 32768
    uint32_t* wt1f    = (uint32_t*)(ws + 7782400);   // 98304 each
    uint32_t* wt1b    = (uint32_t*)(ws + 7880704);
    uint32_t* wt2f    = (uint32_t*)(ws + 7979008);
    uint32_t* wt2b    = (uint32_t*)(ws + 8077312);
    uint32_t* wtd     = (uint32_t*)(ws + 8175616);
    __half*   wih1f_h = (__half*)(ws + 8273920);     // 147456 f16
    __half*   wih1b_h = (__half*)(ws + 8347648);
    __half*   wih2f_h = (__half*)(ws + 8421376);     // 393216 f16
    __half*   wih2b_h = (__half*)(ws + 8617984);
    float*    wihdT   = ws + 8814592;                // 43008
    float*    wadjT   = ws + 8857600;                // 131072
    float*    wfc1T   = ws + 8988672;                // 14336

    prep_all<<<5344, 256, 0, stream>>>(
        whh1f, whh1b, whh2f, whh2b, whhd,
        wt1f, wt1b, wt2f, wt2b, wtd,
        wih1f, wih1b, wih2f, wih2b,
        wih1f_h, wih1b_h, wih2f_h, wih2b_h,
        wihd, wadj, wfc1, wihdT, wadjT, wfc1T,
        x, seqg_h);

    // layer 1
    gemm_mfma<192><<<dim3(64, 12, 2), 256, 0, stream>>>(
        seqg_h, wih1f_h, wih1b_h, bih1f, bih1b, gi_f, gi_b);
    gru_scan<<<128, 512, 0, stream>>>(
        gi_f, gi_b, wt1f, wt1b, bhh1f, bhh1b, y1h, hfin);

    // layer 2 (gi buffers reused; scan2's y1h writes are dead but harmless)
    gemm_mfma<512><<<dim3(64, 12, 2), 256, 0, stream>>>(
        y1h, wih2f_h, wih2b_h, bih2f, bih2b, gi_f, gi_b);
    gru_scan<<<128, 512, 0, stream>>>(
        gi_f, gi_b, wt2f, wt2b, bhh2f, bhh2b, y1h, hfin);

    // decoder head (adj fused)
    decoder_kernel<<<64, 768, 0, stream>>>(
        hfin, wadjT, badj, wtd, wihdT, bihd, bhhd, wfc1T, bfc1,
        (float*)d_out);
}

// Round 16
// 331.798 us; speedup vs baseline: 1.2008x; 1.0417x over previous
//
#include <hip/hip_runtime.h>
#include <hip/hip_fp16.h>
#include <stdint.h>

// ---------------------------------------------------------------------------
// Problem geometry (all compile-time):
//   x: (64, 48, 512, 2, 2) fp32. seq[s,n,f] = x[n, f>>2, 8*s, (f>>1)&1, f&1]
//   (only batch rows n<64 of the 512 matter downstream).
//   Layer1 BiGRU: in=192, H=256, 64 steps. Layer2 BiGRU: in=512, H=256.
//   Only final hiddens of layer2 used. dec_h = w_adj @ [hf,hb] + b_adj.
//   Decoder GRU (in=56, H=256) 6 steps, out = w_fc1@h + b_fc1 -> (64,6,56).
//
// SCAN LEDGER (r2-r15): compiler remats large resident sets; pure stream =
// per-CU L2-port floor 393KB/111B/cyc = 1.47us/step (r10); <128 blocks
// starve (r11); LDS weights in FULL-K shape lose (r12: 32 h-reads/thread
// already tax the LDS port). Split-K (512,1) L16-ask: allocator keeps ~72
// dwords (VGPR 116) -> 92.8us/scan (r9/r15 BEST).
// r16: split-K h-reads are WAVE-UNIFORM BROADCASTS (free) -> LDS port is
// idle -> stage 6/16 chunks per half in LDS (144KB; already 1 blk/CU) so
// L2 (0.74us) and LDS (0.72us) ports run in parallel.
// GEMM: r8->r9 delta shows no-LDS MFMA gemms still ~70us combined (B tile
// streamed 4x redundantly per block, latency-chained) -> stage B in padded
// LDS (stride K+8: 2-way conflict = free), A streamed.
// ---------------------------------------------------------------------------

#define HD 256
#define G3 768
#define NSEQ 64
#define NSTEP 64
#define LSTG 6          // chunks 10..15 of each K-half staged in LDS

typedef _Float16 hvec2 __attribute__((ext_vector_type(2)));
typedef _Float16 f16x8 __attribute__((ext_vector_type(8)));
typedef float f32x4 __attribute__((ext_vector_type(4)));

__device__ __forceinline__ float sigmf(float x) {
    return 1.0f / (1.0f + __expf(-x));
}

#if __has_builtin(__builtin_amdgcn_fdot2)
__device__ __forceinline__ float fdot2u(uint32_t w, uint32_t h, float acc) {
    return __builtin_amdgcn_fdot2(__builtin_bit_cast(hvec2, w),
                                  __builtin_bit_cast(hvec2, h), acc, false);
}
#else
__device__ __forceinline__ float fdot2u(uint32_t w, uint32_t h, float acc) {
    const __half2 wv = __builtin_bit_cast(__half2, w);
    const __half2 hv = __builtin_bit_cast(__half2, h);
    acc += __half2float(wv.x) * __half2float(hv.x);
    acc += __half2float(wv.y) * __half2float(hv.y);
    return acc;
}
#endif

__device__ __forceinline__ uint32_t pkh(float a, float b) {
    uint32_t lo = __half_as_ushort(__float2half_rn(a));
    uint32_t hi = __half_as_ushort(__float2half_rn(b));
    return lo | (hi << 16);
}

#define L10(X) X(0) X(1) X(2) X(3) X(4) X(5) X(6) X(7) X(8) X(9)

// resident-attempt chunks 0..9 per gate row (30 uint4 = 120 dwords ask).
// Allocator keeps what it wants, streams the rest (r9 behavior).
#define LRES(i) \
    const uint4 wr##i = wbase[(i) * G3]; \
    const uint4 wz##i = wbase[(i) * G3 + 256]; \
    const uint4 wn##i = wbase[(i) * G3 + 512];

#define DRES(i) { \
    const uint4 hp = *(const uint4*)&hb[hoff + 4 * (i)]; \
    ar0 = fdot2u(wr##i.x, hp.x, ar0); ar1 = fdot2u(wr##i.y, hp.y, ar1); \
    ar0 = fdot2u(wr##i.z, hp.z, ar0); ar1 = fdot2u(wr##i.w, hp.w, ar1); \
    az0 = fdot2u(wz##i.x, hp.x, az0); az1 = fdot2u(wz##i.y, hp.y, az1); \
    az0 = fdot2u(wz##i.z, hp.z, az0); az1 = fdot2u(wz##i.w, hp.w, az1); \
    an0 = fdot2u(wn##i.x, hp.x, an0); an1 = fdot2u(wn##i.y, hp.y, an1); \
    an0 = fdot2u(wn##i.z, hp.z, an0); an1 = fdot2u(wn##i.w, hp.w, an1); }

// ---------------- merged weight/input prep (one launch) ----------------
__global__ __launch_bounds__(256) void prep_all(
    const float* __restrict__ whh1f, const float* __restrict__ whh1b,
    const float* __restrict__ whh2f, const float* __restrict__ whh2b,
    const float* __restrict__ whhd,
    uint32_t* __restrict__ wt1f, uint32_t* __restrict__ wt1b,
    uint32_t* __restrict__ wt2f, uint32_t* __restrict__ wt2b,
    uint32_t* __restrict__ wtd,
    const float* __restrict__ wih1f, const float* __restrict__ wih1b,
    const float* __restrict__ wih2f, const float* __restrict__ wih2b,
    __half* __restrict__ wih1f_h, __half* __restrict__ wih1b_h,
    __half* __restrict__ wih2f_h, __half* __restrict__ wih2b_h,
    const float* __restrict__ wihd, const float* __restrict__ wadj,
    const float* __restrict__ wfc1,
    float* __restrict__ wihdT, float* __restrict__ wadjT,
    float* __restrict__ wfc1T,
    const float* __restrict__ x, __half* __restrict__ seqg)
{
    const int b   = blockIdx.x;
    const int tid = threadIdx.x;

    if (b < 480) {
        // Whh repack -> uint4[q*768 + j], q=0..31 holds k=8q..8q+7 of row j
        const int y = b / 96;
        const float* w; uint32_t* o;
        switch (y) {
            case 0: w = whh1f; o = wt1f; break;
            case 1: w = whh1b; o = wt1b; break;
            case 2: w = whh2f; o = wt2f; break;
            case 3: w = whh2b; o = wt2b; break;
            default: w = whhd; o = wtd; break;
        }
        const int idx = (b % 96) * 256 + tid;   // 24576
        const int j = idx >> 5, q = idx & 31;
        const float4 fa = *(const float4*)(w + j * HD + 8 * q);
        const float4 fb = *(const float4*)(w + j * HD + 8 * q + 4);
        uint4 r;
        r.x = pkh(fa.x, fa.y); r.y = pkh(fa.z, fa.w);
        r.z = pkh(fb.x, fb.y); r.w = pkh(fb.z, fb.w);
        ((uint4*)o)[q * G3 + j] = r;
    } else if (b < 1536) {
        const float* s; __half* d; int i4;
        if (b < 624)       { s = wih1f; d = wih1f_h; i4 = (b - 480) * 256 + tid; }
        else if (b < 768)  { s = wih1b; d = wih1b_h; i4 = (b - 624) * 256 + tid; }
        else if (b < 1152) { s = wih2f; d = wih2f_h; i4 = (b - 768) * 256 + tid; }
        else               { s = wih2b; d = wih2b_h; i4 = (b - 1152) * 256 + tid; }
        const float4 v = *(const float4*)(s + (size_t)i4 * 4);
        __half2 lo; lo.x = __float2half_rn(v.x); lo.y = __float2half_rn(v.y);
        __half2 hi; hi.x = __float2half_rn(v.z); hi.y = __float2half_rn(v.w);
        *(__half2*)(d + (size_t)i4 * 4)     = lo;
        *(__half2*)(d + (size_t)i4 * 4 + 2) = hi;
    } else if (b < 2272) {
        const int idx = (b - 1536) * 256 + tid;  // 188416
        if (idx < 43008) {
            int v = idx / G3, j = idx % G3;
            wihdT[idx] = wihd[j * 56 + v];
        } else if (idx < 43008 + 131072) {
            int i2 = idx - 43008;
            int f = i2 / HD, i = i2 % HD;
            wadjT[i2] = wadj[i * 512 + f];
        } else {
            int i3 = idx - 174080;
            int k = i3 / 56, v = i3 % 56;
            wfc1T[i3] = wfc1[v * HD + k];
        }
    } else {
        const int idx = (b - 2272) * 256 + tid;  // 786432
        const int f = idx % 192;
        const int m = idx / 192;
        const int n = m >> 6, s = m & 63;
        seqg[idx] = __float2half(
            x[n * 98304 + (f >> 2) * 2048 + s * 32 + (f & 3)]);
    }
}

// ---------------- f16 MFMA GEMM, B tile staged in LDS ----------------
// C[m][j] = sum_k A[m][k]*B[j][k] + bias[j]; M=4096, N=768, K in {192,512}.
// grid=(64, 12, 2); 4 waves; B tile (64 rows x K) staged once in LDS with
// row stride K+8 (2-way bank aliasing = free); A streamed from L2.
// C/D layout (HW-verified): col=lane&15, row=(lane>>4)*4+reg.
template <int K>
__global__ __launch_bounds__(256) void gemm_mfma(
    const __half* __restrict__ A,
    const __half* __restrict__ B0, const __half* __restrict__ B1,
    const float* __restrict__ bias0, const float* __restrict__ bias1,
    float* __restrict__ C0, float* __restrict__ C1)
{
    extern __shared__ __half Bs[];            // [64][K+8]
    constexpr int LDB = K + 8;

    const __half* B    = blockIdx.z ? B1 : B0;
    const float*  bias = blockIdx.z ? bias1 : bias0;
    float*        C    = blockIdx.z ? C1 : C0;
    const int m0 = blockIdx.x * 64;
    const int n0 = blockIdx.y * 64;
    const int w  = threadIdx.x >> 6;
    const int l  = threadIdx.x & 63;
    const int lr = l & 15;
    const int lk = (l >> 4) * 8;

    // stage B rows n0..n0+63 (contiguous 64*K f16) into padded LDS
    const __half* bsrc = B + (size_t)n0 * K;
#pragma unroll
    for (int i = threadIdx.x; i < 64 * K / 8; i += 256) {
        const int r = i / (K / 8), g = i % (K / 8);
        *(f16x8*)(Bs + r * LDB + g * 8) = *(const f16x8*)(bsrc + i * 8);
    }
    __syncthreads();

    const __half* arow = A + (size_t)(m0 + w * 16 + lr) * K + lk;
    const __half* brow = Bs + lr * LDB + lk;

    f32x4 acc0 = {0.f, 0.f, 0.f, 0.f};
    f32x4 acc1 = acc0, acc2 = acc0, acc3 = acc0;

#pragma unroll
    for (int k0 = 0; k0 < K; k0 += 32) {
        const f16x8 a  = *(const f16x8*)(arow + k0);
        const f16x8 b0 = *(const f16x8*)(brow + k0);
        const f16x8 b1 = *(const f16x8*)(brow + 16 * LDB + k0);
        const f16x8 b2 = *(const f16x8*)(brow + 32 * LDB + k0);
        const f16x8 b3 = *(const f16x8*)(brow + 48 * LDB + k0);
        acc0 = __builtin_amdgcn_mfma_f32_16x16x32_f16(a, b0, acc0, 0, 0, 0);
        acc1 = __builtin_amdgcn_mfma_f32_16x16x32_f16(a, b1, acc1, 0, 0, 0);
        acc2 = __builtin_amdgcn_mfma_f32_16x16x32_f16(a, b2, acc2, 0, 0, 0);
        acc3 = __builtin_amdgcn_mfma_f32_16x16x32_f16(a, b3, acc3, 0, 0, 0);
    }

    const int crow = m0 + w * 16 + (l >> 4) * 4;
    const int ccol = n0 + lr;
    float* cp = C + (size_t)crow * G3 + ccol;
    const float bb0 = bias[ccol];
    const float bb1 = bias[ccol + 16];
    const float bb2 = bias[ccol + 32];
    const float bb3 = bias[ccol + 48];
#pragma unroll
    for (int j = 0; j < 4; ++j) {
        cp[(size_t)j * G3 +  0] = acc0[j] + bb0;
        cp[(size_t)j * G3 + 16] = acc1[j] + bb1;
        cp[(size_t)j * G3 + 32] = acc2[j] + bb2;
        cp[(size_t)j * G3 + 48] = acc3[j] + bb3;
    }
}

// ---------------- GRU scan: split-K + LDS-staged chunk tail ----------------
// grid = 128 blocks: dir = blockIdx.x&1, n = blockIdx.x>>1.
// 512 threads: thread (kh=t>>8, tr=t&255) owns gate rows {tr,256+tr,512+tr}
// for K-half kh. Chunks 0..9: resident-attempt (allocator keeps ~6, streams
// rest — r9 measured optimum). Chunks 10..15: staged ONCE in 144KB dynamic
// LDS; per-step reads ride the otherwise-idle LDS port (h-reads are
// wave-uniform broadcasts = free). kh==1 prefetches gi during gate phase.
__global__ __launch_bounds__(512, 1) void gru_scan(
    const float* __restrict__ giF, const float* __restrict__ giB,
    const uint32_t* __restrict__ wTF, const uint32_t* __restrict__ wTB,
    const float* __restrict__ bhhF, const float* __restrict__ bhhB,
    __half* __restrict__ y1h, float* __restrict__ hfin)
{
    extern __shared__ __align__(16) uint4 wlds[];   // [2][LSTG][3][256]

    const int dir = blockIdx.x & 1;
    const int n   = blockIdx.x >> 1;
    const int t   = threadIdx.x;
    const int tr  = t & 255;
    const int kh  = t >> 8;
    const int hoff = kh * 64;        // u32 offset into h buffer
    const float* gi  = dir ? giB : giF;
    const float* bhh = dir ? bhhB : bhhF;
    const uint4* wbase = (const uint4*)(dir ? wTB : wTF)
                       + (size_t)(kh * 16) * G3 + tr;

    __shared__ __align__(16) uint32_t h1u[2][HD / 2];  // h as f16x2, dbuf
    __shared__ float ph_r[HD], ph_z[HD], ph_n[HD];     // upper-half partials
    __shared__ float gin[2][G3];                       // gi double buffer

    // stage chunks 10..15 of this thread's 3 gate rows
#pragma unroll
    for (int c = 0; c < LSTG; ++c) {
        wlds[((kh * LSTG + c) * 3 + 0) * 256 + tr] = wbase[(10 + c) * G3];
        wlds[((kh * LSTG + c) * 3 + 1) * 256 + tr] = wbase[(10 + c) * G3 + 256];
        wlds[((kh * LSTG + c) * 3 + 2) * 256 + tr] = wbase[(10 + c) * G3 + 512];
    }

    L10(LRES)
    const float bhr = bhh[tr], bhz = bhh[256 + tr], bhn = bhh[512 + tr];

    const float* gbase = gi + (size_t)n * NSTEP * G3;
    const int s0 = dir ? (NSTEP - 1) : 0;
#pragma unroll
    for (int i = t; i < G3; i += 512) gin[0][i] = gbase[s0 * G3 + i];

    float h_own = 0.0f;
    if (t < HD / 2) h1u[0][t] = 0u;
    __syncthreads();

    int s = s0;
    for (int step = 0; step < NSTEP; ++step) {
        const uint32_t* hb = h1u[step & 1];
        float ar0 = 0.f, ar1 = 0.f;
        float az0 = 0.f, az1 = 0.f;
        float an0 = 0.f, an1 = 0.f;
        L10(DRES)
        // LDS-staged chunks 10..15
#pragma unroll
        for (int c = 0; c < LSTG; ++c) {
            const uint4 hp = *(const uint4*)&hb[hoff + 4 * (10 + c)];
            const uint4 wrl = wlds[((kh * LSTG + c) * 3 + 0) * 256 + tr];
            const uint4 wzl = wlds[((kh * LSTG + c) * 3 + 1) * 256 + tr];
            const uint4 wnl = wlds[((kh * LSTG + c) * 3 + 2) * 256 + tr];
            ar0 = fdot2u(wrl.x, hp.x, ar0); ar1 = fdot2u(wrl.y, hp.y, ar1);
            ar0 = fdot2u(wrl.z, hp.z, ar0); ar1 = fdot2u(wrl.w, hp.w, ar1);
            az0 = fdot2u(wzl.x, hp.x, az0); az1 = fdot2u(wzl.y, hp.y, az1);
            az0 = fdot2u(wzl.z, hp.z, az0); az1 = fdot2u(wzl.w, hp.w, az1);
            an0 = fdot2u(wnl.x, hp.x, an0); an1 = fdot2u(wnl.y, hp.y, an1);
            an0 = fdot2u(wnl.z, hp.z, an0); an1 = fdot2u(wnl.w, hp.w, an1);
        }

        if (kh) {
            ph_r[tr] = ar0 + ar1;
            ph_z[tr] = az0 + az1;
            ph_n[tr] = an0 + an1;
        }
        __syncthreads();
        const int s_nxt = dir ? (step < NSTEP - 1 ? NSTEP - 2 - step : 0)
                              : (step < NSTEP - 1 ? step + 1 : NSTEP - 1);
        if (kh == 0) {
            const float* gcur = gin[step & 1];
            const float ghr = (ar0 + ar1) + ph_r[tr] + bhr;
            const float ghz = (az0 + az1) + ph_z[tr] + bhz;
            const float ghn = (an0 + an1) + ph_n[tr] + bhn;
            const float r  = sigmf(gcur[tr] + ghr);
            const float z  = sigmf(gcur[256 + tr] + ghz);
            const float nn = tanhf(gcur[512 + tr] + r * ghn);
            const float hnew = (1.0f - z) * nn + z * h_own;
            h_own = hnew;
            const __half hh = __float2half(hnew);
            ((__half*)h1u[(step + 1) & 1])[tr] = hh;
            y1h[(size_t)(n * NSTEP + s) * 512 + dir * HD + tr] = hh;
        } else {
            float* gnxt = gin[(step + 1) & 1];
            gnxt[tr]       = gbase[s_nxt * G3 + tr];
            gnxt[256 + tr] = gbase[s_nxt * G3 + 256 + tr];
            gnxt[512 + tr] = gbase[s_nxt * G3 + 512 + tr];
        }
        s = s_nxt;
        __syncthreads();
    }
    if (kh == 0)
        hfin[(size_t)(dir * NSEQ + n) * HD + tr] = h_own;
}

// ---------------- decoder (adj fused): 64 blocks x 768 threads -------------
__global__ __launch_bounds__(768, 3) void decoder_kernel(
    const float* __restrict__ hfin, const float* __restrict__ wadjT,
    const float* __restrict__ badj, const uint32_t* __restrict__ wTd,
    const float* __restrict__ wihdT, const float* __restrict__ bihd,
    const float* __restrict__ bhhd, const float* __restrict__ wfc1T,
    const float* __restrict__ bfc1, float* __restrict__ out)
{
    const int n = blockIdx.x, t = threadIdx.x;
    const uint4* wq = (const uint4*)wTd + t;

    __shared__ __align__(16) uint32_t h1u[2][HD / 2];
    __shared__ float comb[512];
    __shared__ float ghs[G3], gis[G3];
    __shared__ float hfp[HD];
    __shared__ float inp[56];
    __shared__ float pf1[448];

    const float bi = bihd[t], bh = bhhd[t];

    if (t < 512)
        comb[t] = (t < 256) ? hfin[(size_t)n * HD + t]
                            : hfin[(size_t)(NSEQ + n) * HD + (t - 256)];
    if (t < 56) inp[t] = 0.0f;
    __syncthreads();

    float h_own = 0.0f;
    if (t < HD) {
        float acc = badj[t];
#pragma unroll 8
        for (int f = 0; f < 512; ++f) acc += wadjT[f * HD + t] * comb[f];
        h_own = acc;
        ((__half*)h1u[0])[t] = __float2half(acc);
        hfp[t] = acc;
    }
    __syncthreads();

    for (int step = 0; step < 6; ++step) {
        const uint32_t* hb = h1u[step & 1];
        float a0 = 0.f, a1 = 0.f;
#pragma unroll 8
        for (int q = 0; q < 32; ++q) {
            const uint4 w = wq[q * G3];
            const uint4 hp = *(const uint4*)&hb[4 * q];
            a0 = fdot2u(w.x, hp.x, a0); a1 = fdot2u(w.y, hp.y, a1);
            a0 = fdot2u(w.z, hp.z, a0); a1 = fdot2u(w.w, hp.w, a1);
        }
        float ai = bi;
#pragma unroll 8
        for (int v = 0; v < 56; ++v) ai += wihdT[v * G3 + t] * inp[v];
        ghs[t] = a0 + a1 + bh;
        gis[t] = ai;
        __syncthreads();
        if (t < HD) {
            const float r  = sigmf(gis[t] + ghs[t]);
            const float z  = sigmf(gis[HD + t] + ghs[HD + t]);
            const float nn = tanhf(gis[2 * HD + t] + r * ghs[2 * HD + t]);
            const float hnew = (1.0f - z) * nn + z * h_own;
            h_own = hnew;
            ((__half*)h1u[(step + 1) & 1])[t] = __float2half(hnew);
            hfp[t] = hnew;
        }
        __syncthreads();
        if (t < 448) {
            const int v = t >> 3, g = t & 7;
            float o = 0.f;
#pragma unroll
            for (int k2 = 0; k2 < 32; ++k2)
                o += wfc1T[(g * 32 + k2) * 56 + v] * hfp[g * 32 + k2];
            pf1[t] = o;
        }
        __syncthreads();
        if (t < 56) {
            float o = bfc1[t];
#pragma unroll
            for (int g = 0; g < 8; ++g) o += pf1[t * 8 + g];
            out[(size_t)n * 336 + step * 56 + t] = o;
            inp[t] = o;
        }
        __syncthreads();
    }
}

// ---------------------------------------------------------------------------
extern "C" void kernel_launch(void* const* d_in, const int* in_sizes, int n_in,
                              void* d_out, int out_size, void* d_ws, size_t ws_size,
                              hipStream_t stream)
{
    const float* x      = (const float*)d_in[0];
    const float* wih1f  = (const float*)d_in[1];
    const float* whh1f  = (const float*)d_in[2];
    const float* bih1f  = (const float*)d_in[3];
    const float* bhh1f  = (const float*)d_in[4];
    const float* wih1b  = (const float*)d_in[5];
    const float* whh1b  = (const float*)d_in[6];
    const float* bih1b  = (const float*)d_in[7];
    const float* bhh1b  = (const float*)d_in[8];
    const float* wih2f  = (const float*)d_in[9];
    const float* whh2f  = (const float*)d_in[10];
    const float* bih2f  = (const float*)d_in[11];
    const float* bhh2f  = (const float*)d_in[12];
    const float* wih2b  = (const float*)d_in[13];
    const float* whh2b  = (const float*)d_in[14];
    const float* bih2b  = (const float*)d_in[15];
    const float* bhh2b  = (const float*)d_in[16];
    const float* wihd   = (const float*)d_in[17];
    const float* whhd   = (const float*)d_in[18];
    const float* bihd   = (const float*)d_in[19];
    const float* bhhd   = (const float*)d_in[20];
    const float* wfc1   = (const float*)d_in[21];
    const float* bfc1   = (const float*)d_in[22];
    const float* wadj   = (const float*)d_in[23];
    const float* badj   = (const float*)d_in[24];

    float* ws = (float*)d_ws;
    __half*   seqg_h  = (__half*)(ws + 0);           // 786432 f16
    float*    gi_f    = ws + 393216;                 // 3145728
    float*    gi_b    = ws + 3538944;                // 3145728
    __half*   y1h     = (__half*)(ws + 6684672);     // 2097152 f16
    float*    hfin    = ws + 7733248;                // 32768
    uint32_t* wt1f    = (uint32_t*)(ws + 7782400);   // 98304 each
    uint32_t* wt1b    = (uint32_t*)(ws + 7880704);
    uint32_t* wt2f    = (uint32_t*)(ws + 7979008);
    uint32_t* wt2b    = (uint32_t*)(ws + 8077312);
    uint32_t* wtd     = (uint32_t*)(ws + 8175616);
    __half*   wih1f_h = (__half*)(ws + 8273920);     // 147456 f16
    __half*   wih1b_h = (__half*)(ws + 8347648);
    __half*   wih2f_h = (__half*)(ws + 8421376);     // 393216 f16
    __half*   wih2b_h = (__half*)(ws + 8617984);
    float*    wihdT   = ws + 8814592;                // 43008
    float*    wadjT   = ws + 8857600;                // 131072
    float*    wfc1T   = ws + 8988672;                // 14336

    // dynamic-LDS opt-ins (>64KB): scan 144KB, gemm<512> 66560B
    const int scan_lds = 2 * LSTG * 3 * 256 * 16;    // 147456 B
    hipFuncSetAttribute((const void*)gru_scan,
                        hipFuncAttributeMaxDynamicSharedMemorySize, scan_lds);
    const int g192_lds = 64 * (192 + 8) * 2;         // 25600 B
    const int g512_lds = 64 * (512 + 8) * 2;         // 66560 B
    hipFuncSetAttribute((const void*)gemm_mfma<512>,
                        hipFuncAttributeMaxDynamicSharedMemorySize, g512_lds);

    prep_all<<<5344, 256, 0, stream>>>(
        whh1f, whh1b, whh2f, whh2b, whhd,
        wt1f, wt1b, wt2f, wt2b, wtd,
        wih1f, wih1b, wih2f, wih2b,
        wih1f_h, wih1b_h, wih2f_h, wih2b_h,
        wihd, wadj, wfc1, wihdT, wadjT, wfc1T,
        x, seqg_h);

    // layer 1
    gemm_mfma<192><<<dim3(64, 12, 2), 256, g192_lds, stream>>>(
        seqg_h, wih1f_h, wih1b_h, bih1f, bih1b, gi_f, gi_b);
    gru_scan<<<128, 512, scan_lds, stream>>>(
        gi_f, gi_b, wt1f, wt1b, bhh1f, bhh1b, y1h, hfin);

    // layer 2 (gi buffers reused; scan2's y1h writes are dead but harmless)
    gemm_mfma<512><<<dim3(64, 12, 2), 256, g512_lds, stream>>>(
        y1h, wih2f_h, wih2b_h, bih2f, bih2b, gi_f, gi_b);
    gru_scan<<<128, 512, scan_lds, stream>>>(
        gi_f, gi_b, wt2f, wt2b, bhh2f, bhh2b, y1h, hfin);

    // decoder head (adj fused)
    decoder_kernel<<<64, 768, 0, stream>>>(
        hfin, wadjT, badj, wtd, wihdT, bihd, bhhd, wfc1T, bfc1,
        (float*)d_out);
}

// Round 17
// 302.886 us; speedup vs baseline: 1.3155x; 1.0955x over previous
//
#include <hip/hip_runtime.h>
#include <hip/hip_fp16.h>
#include <stdint.h>

// ---------------------------------------------------------------------------
// Problem geometry (all compile-time):
//   x: (64, 48, 512, 2, 2) fp32. seq[s,n,f] = x[n, f>>2, 8*s, (f>>1)&1, f&1]
//   (only batch rows n<64 of the 512 matter downstream).
//   Layer1 BiGRU: in=192, H=256, 64 steps. Layer2 BiGRU: in=512, H=256.
//   Only final hiddens of layer2 used. dec_h = w_adj @ [hf,hb] + b_adj.
//   Decoder GRU (in=56, H=256) 6 steps, out = w_fc1@h + b_fc1 -> (64,6,56).
//
// SCAN LEDGER — CLOSED (r2-r16). The r9 split-K shape is the measured
// optimum (92.8us/scan, VGPR 116: allocator voluntarily holds ~72 dwords,
// streams the rest). Every perturbation lost:
//   * forced residency (pins / AGPR asm / alias tricks): remat or spill;
//   * pure stream: L2-port floor 1.47us/step (r10);
//   * <128 blocks: latency starvation (r11);
//   * LDS-staged weights, full-K shape: h-read port pressure (r12);
//   * LDS-staged tail, split-K shape: displaces residency, VGPR 116->84
//     and 107us (r16);
//   * 1024-thr 4-way split: full remat + partial overhead (r14);
//   * resident-ask tuning L8/L5: equal or worse (r13/r14).
// Per-step model: 0.86us L2 stream + 0.64us VALU, serialized by load->dot
// dependency at 2 waves/SIMD. Structural floor for this recurrence.
// GEMM (r16 WIN, keep): B tile staged in padded LDS (stride K+8), A
// streamed; saved ~40us vs no-LDS MFMA.
// ---------------------------------------------------------------------------

#define HD 256
#define G3 768
#define NSEQ 64
#define NSTEP 64

typedef _Float16 hvec2 __attribute__((ext_vector_type(2)));
typedef _Float16 f16x8 __attribute__((ext_vector_type(8)));
typedef float f32x4 __attribute__((ext_vector_type(4)));

__device__ __forceinline__ float sigmf(float x) {
    return 1.0f / (1.0f + __expf(-x));
}

#if __has_builtin(__builtin_amdgcn_fdot2)
__device__ __forceinline__ float fdot2u(uint32_t w, uint32_t h, float acc) {
    return __builtin_amdgcn_fdot2(__builtin_bit_cast(hvec2, w),
                                  __builtin_bit_cast(hvec2, h), acc, false);
}
#else
__device__ __forceinline__ float fdot2u(uint32_t w, uint32_t h, float acc) {
    const __half2 wv = __builtin_bit_cast(__half2, w);
    const __half2 hv = __builtin_bit_cast(__half2, h);
    acc += __half2float(wv.x) * __half2float(hv.x);
    acc += __half2float(wv.y) * __half2float(hv.y);
    return acc;
}
#endif

__device__ __forceinline__ uint32_t pkh(float a, float b) {
    uint32_t lo = __half_as_ushort(__float2half_rn(a));
    uint32_t hi = __half_as_ushort(__float2half_rn(b));
    return lo | (hi << 16);
}

#define L16(X) X(0) X(1) X(2) X(3) X(4) X(5) X(6) X(7) \
  X(8) X(9) X(10) X(11) X(12) X(13) X(14) X(15)

// resident-attempt: 16 chunks per gate row x 3 rows = 48 uint4 = 192 dwords.
// Allocator keeps ~6 chunks (72 dwords, VGPR 116) and streams the rest —
// measured BEST at 92.8us/scan (r9/r15). Do not "fix"; every alternative lost.
#define LRES(i) \
    const uint4 wr##i = wbase[(i) * G3]; \
    const uint4 wz##i = wbase[(i) * G3 + 256]; \
    const uint4 wn##i = wbase[(i) * G3 + 512];

#define DRES(i) { \
    const uint4 hp = *(const uint4*)&hb[hoff + 4 * (i)]; \
    ar0 = fdot2u(wr##i.x, hp.x, ar0); ar1 = fdot2u(wr##i.y, hp.y, ar1); \
    ar0 = fdot2u(wr##i.z, hp.z, ar0); ar1 = fdot2u(wr##i.w, hp.w, ar1); \
    az0 = fdot2u(wz##i.x, hp.x, az0); az1 = fdot2u(wz##i.y, hp.y, az1); \
    az0 = fdot2u(wz##i.z, hp.z, az0); az1 = fdot2u(wz##i.w, hp.w, az1); \
    an0 = fdot2u(wn##i.x, hp.x, an0); an1 = fdot2u(wn##i.y, hp.y, an1); \
    an0 = fdot2u(wn##i.z, hp.z, an0); an1 = fdot2u(wn##i.w, hp.w, an1); }

// ---------------- merged weight/input prep (one launch) ----------------
__global__ __launch_bounds__(256) void prep_all(
    const float* __restrict__ whh1f, const float* __restrict__ whh1b,
    const float* __restrict__ whh2f, const float* __restrict__ whh2b,
    const float* __restrict__ whhd,
    uint32_t* __restrict__ wt1f, uint32_t* __restrict__ wt1b,
    uint32_t* __restrict__ wt2f, uint32_t* __restrict__ wt2b,
    uint32_t* __restrict__ wtd,
    const float* __restrict__ wih1f, const float* __restrict__ wih1b,
    const float* __restrict__ wih2f, const float* __restrict__ wih2b,
    __half* __restrict__ wih1f_h, __half* __restrict__ wih1b_h,
    __half* __restrict__ wih2f_h, __half* __restrict__ wih2b_h,
    const float* __restrict__ wihd, const float* __restrict__ wadj,
    const float* __restrict__ wfc1,
    float* __restrict__ wihdT, float* __restrict__ wadjT,
    float* __restrict__ wfc1T,
    const float* __restrict__ x, __half* __restrict__ seqg)
{
    const int b   = blockIdx.x;
    const int tid = threadIdx.x;

    if (b < 480) {
        // Whh repack -> uint4[q*768 + j], q=0..31 holds k=8q..8q+7 of row j
        const int y = b / 96;
        const float* w; uint32_t* o;
        switch (y) {
            case 0: w = whh1f; o = wt1f; break;
            case 1: w = whh1b; o = wt1b; break;
            case 2: w = whh2f; o = wt2f; break;
            case 3: w = whh2b; o = wt2b; break;
            default: w = whhd; o = wtd; break;
        }
        const int idx = (b % 96) * 256 + tid;   // 24576
        const int j = idx >> 5, q = idx & 31;
        const float4 fa = *(const float4*)(w + j * HD + 8 * q);
        const float4 fb = *(const float4*)(w + j * HD + 8 * q + 4);
        uint4 r;
        r.x = pkh(fa.x, fa.y); r.y = pkh(fa.z, fa.w);
        r.z = pkh(fb.x, fb.y); r.w = pkh(fb.z, fb.w);
        ((uint4*)o)[q * G3 + j] = r;
    } else if (b < 1536) {
        const float* s; __half* d; int i4;
        if (b < 624)       { s = wih1f; d = wih1f_h; i4 = (b - 480) * 256 + tid; }
        else if (b < 768)  { s = wih1b; d = wih1b_h; i4 = (b - 624) * 256 + tid; }
        else if (b < 1152) { s = wih2f; d = wih2f_h; i4 = (b - 768) * 256 + tid; }
        else               { s = wih2b; d = wih2b_h; i4 = (b - 1152) * 256 + tid; }
        const float4 v = *(const float4*)(s + (size_t)i4 * 4);
        __half2 lo; lo.x = __float2half_rn(v.x); lo.y = __float2half_rn(v.y);
        __half2 hi; hi.x = __float2half_rn(v.z); hi.y = __float2half_rn(v.w);
        *(__half2*)(d + (size_t)i4 * 4)     = lo;
        *(__half2*)(d + (size_t)i4 * 4 + 2) = hi;
    } else if (b < 2272) {
        const int idx = (b - 1536) * 256 + tid;  // 188416
        if (idx < 43008) {
            int v = idx / G3, j = idx % G3;
            wihdT[idx] = wihd[j * 56 + v];
        } else if (idx < 43008 + 131072) {
            int i2 = idx - 43008;
            int f = i2 / HD, i = i2 % HD;
            wadjT[i2] = wadj[i * 512 + f];
        } else {
            int i3 = idx - 174080;
            int k = i3 / 56, v = i3 % 56;
            wfc1T[i3] = wfc1[v * HD + k];
        }
    } else {
        const int idx = (b - 2272) * 256 + tid;  // 786432
        const int f = idx % 192;
        const int m = idx / 192;
        const int n = m >> 6, s = m & 63;
        seqg[idx] = __float2half(
            x[n * 98304 + (f >> 2) * 2048 + s * 32 + (f & 3)]);
    }
}

// ---------------- f16 MFMA GEMM, B tile staged in LDS (r16 WIN) -----------
// C[m][j] = sum_k A[m][k]*B[j][k] + bias[j]; M=4096, N=768, K in {192,512}.
// grid=(64, 12, 2); 4 waves; B tile (64 rows x K) staged once in LDS with
// row stride K+8 (2-way bank aliasing = free); A streamed from L2.
// C/D layout (HW-verified): col=lane&15, row=(lane>>4)*4+reg.
template <int K>
__global__ __launch_bounds__(256) void gemm_mfma(
    const __half* __restrict__ A,
    const __half* __restrict__ B0, const __half* __restrict__ B1,
    const float* __restrict__ bias0, const float* __restrict__ bias1,
    float* __restrict__ C0, float* __restrict__ C1)
{
    extern __shared__ __half Bs[];            // [64][K+8]
    constexpr int LDB = K + 8;

    const __half* B    = blockIdx.z ? B1 : B0;
    const float*  bias = blockIdx.z ? bias1 : bias0;
    float*        C    = blockIdx.z ? C1 : C0;
    const int m0 = blockIdx.x * 64;
    const int n0 = blockIdx.y * 64;
    const int w  = threadIdx.x >> 6;
    const int l  = threadIdx.x & 63;
    const int lr = l & 15;
    const int lk = (l >> 4) * 8;

    // stage B rows n0..n0+63 (contiguous 64*K f16) into padded LDS
    const __half* bsrc = B + (size_t)n0 * K;
#pragma unroll
    for (int i = threadIdx.x; i < 64 * K / 8; i += 256) {
        const int r = i / (K / 8), g = i % (K / 8);
        *(f16x8*)(Bs + r * LDB + g * 8) = *(const f16x8*)(bsrc + i * 8);
    }
    __syncthreads();

    const __half* arow = A + (size_t)(m0 + w * 16 + lr) * K + lk;
    const __half* brow = Bs + lr * LDB + lk;

    f32x4 acc0 = {0.f, 0.f, 0.f, 0.f};
    f32x4 acc1 = acc0, acc2 = acc0, acc3 = acc0;

#pragma unroll
    for (int k0 = 0; k0 < K; k0 += 32) {
        const f16x8 a  = *(const f16x8*)(arow + k0);
        const f16x8 b0 = *(const f16x8*)(brow + k0);
        const f16x8 b1 = *(const f16x8*)(brow + 16 * LDB + k0);
        const f16x8 b2 = *(const f16x8*)(brow + 32 * LDB + k0);
        const f16x8 b3 = *(const f16x8*)(brow + 48 * LDB + k0);
        acc0 = __builtin_amdgcn_mfma_f32_16x16x32_f16(a, b0, acc0, 0, 0, 0);
        acc1 = __builtin_amdgcn_mfma_f32_16x16x32_f16(a, b1, acc1, 0, 0, 0);
        acc2 = __builtin_amdgcn_mfma_f32_16x16x32_f16(a, b2, acc2, 0, 0, 0);
        acc3 = __builtin_amdgcn_mfma_f32_16x16x32_f16(a, b3, acc3, 0, 0, 0);
    }

    const int crow = m0 + w * 16 + (l >> 4) * 4;
    const int ccol = n0 + lr;
    float* cp = C + (size_t)crow * G3 + ccol;
    const float bb0 = bias[ccol];
    const float bb1 = bias[ccol + 16];
    const float bb2 = bias[ccol + 32];
    const float bb3 = bias[ccol + 48];
#pragma unroll
    for (int j = 0; j < 4; ++j) {
        cp[(size_t)j * G3 +  0] = acc0[j] + bb0;
        cp[(size_t)j * G3 + 16] = acc1[j] + bb1;
        cp[(size_t)j * G3 + 32] = acc2[j] + bb2;
        cp[(size_t)j * G3 + 48] = acc3[j] + bb3;
    }
}

// ---------------- GRU scan (r9 shape — measured optimum, 92.8us) -----------
// grid = 128 blocks: dir = blockIdx.x&1, n = blockIdx.x>>1.
// 512 threads: thread (kh=t>>8, tr=t&255) owns gate rows {tr,256+tr,512+tr}
// for K-half kh. All 16 chunks declared resident; allocator keeps ~6 and
// streams the rest (VGPR 116). kh==1 half prefetches next step's gi into
// LDS during the gate phase. h dbuf f16x2 in LDS (wave-uniform broadcasts).
__global__ __launch_bounds__(512, 1) void gru_scan(
    const float* __restrict__ giF, const float* __restrict__ giB,
    const uint32_t* __restrict__ wTF, const uint32_t* __restrict__ wTB,
    const float* __restrict__ bhhF, const float* __restrict__ bhhB,
    __half* __restrict__ y1h, float* __restrict__ hfin)
{
    const int dir = blockIdx.x & 1;
    const int n   = blockIdx.x >> 1;
    const int t   = threadIdx.x;
    const int tr  = t & 255;
    const int kh  = t >> 8;
    const int hoff = kh * 64;        // u32 offset into h buffer
    const float* gi  = dir ? giB : giF;
    const float* bhh = dir ? bhhB : bhhF;
    const uint4* wbase = (const uint4*)(dir ? wTB : wTF)
                       + (size_t)(kh * 16) * G3 + tr;

    __shared__ __align__(16) uint32_t h1u[2][HD / 2];  // h as f16x2, dbuf
    __shared__ float ph_r[HD], ph_z[HD], ph_n[HD];     // upper-half partials
    __shared__ float gin[2][G3];                       // gi double buffer

    L16(LRES)
    const float bhr = bhh[tr], bhz = bhh[256 + tr], bhn = bhh[512 + tr];

    const float* gbase = gi + (size_t)n * NSTEP * G3;
    const int s0 = dir ? (NSTEP - 1) : 0;
#pragma unroll
    for (int i = t; i < G3; i += 512) gin[0][i] = gbase[s0 * G3 + i];

    float h_own = 0.0f;
    if (t < HD / 2) h1u[0][t] = 0u;
    __syncthreads();

    int s = s0;
    for (int step = 0; step < NSTEP; ++step) {
        const uint32_t* hb = h1u[step & 1];
        float ar0 = 0.f, ar1 = 0.f;
        float az0 = 0.f, az1 = 0.f;
        float an0 = 0.f, an1 = 0.f;
        L16(DRES)

        if (kh) {
            ph_r[tr] = ar0 + ar1;
            ph_z[tr] = az0 + az1;
            ph_n[tr] = an0 + an1;
        }
        __syncthreads();
        const int s_nxt = dir ? (step < NSTEP - 1 ? NSTEP - 2 - step : 0)
                              : (step < NSTEP - 1 ? step + 1 : NSTEP - 1);
        if (kh == 0) {
            const float* gcur = gin[step & 1];
            const float ghr = (ar0 + ar1) + ph_r[tr] + bhr;
            const float ghz = (az0 + az1) + ph_z[tr] + bhz;
            const float ghn = (an0 + an1) + ph_n[tr] + bhn;
            const float r  = sigmf(gcur[tr] + ghr);
            const float z  = sigmf(gcur[256 + tr] + ghz);
            const float nn = tanhf(gcur[512 + tr] + r * ghn);
            const float hnew = (1.0f - z) * nn + z * h_own;
            h_own = hnew;
            const __half hh = __float2half(hnew);
            ((__half*)h1u[(step + 1) & 1])[tr] = hh;
            y1h[(size_t)(n * NSTEP + s) * 512 + dir * HD + tr] = hh;
        } else {
            float* gnxt = gin[(step + 1) & 1];
            gnxt[tr]       = gbase[s_nxt * G3 + tr];
            gnxt[256 + tr] = gbase[s_nxt * G3 + 256 + tr];
            gnxt[512 + tr] = gbase[s_nxt * G3 + 512 + tr];
        }
        s = s_nxt;
        __syncthreads();
    }
    if (kh == 0)
        hfin[(size_t)(dir * NSEQ + n) * HD + tr] = h_own;
}

// ---------------- decoder (adj fused): 64 blocks x 768 threads -------------
__global__ __launch_bounds__(768, 3) void decoder_kernel(
    const float* __restrict__ hfin, const float* __restrict__ wadjT,
    const float* __restrict__ badj, const uint32_t* __restrict__ wTd,
    const float* __restrict__ wihdT, const float* __restrict__ bihd,
    const float* __restrict__ bhhd, const float* __restrict__ wfc1T,
    const float* __restrict__ bfc1, float* __restrict__ out)
{
    const int n = blockIdx.x, t = threadIdx.x;
    const uint4* wq = (const uint4*)wTd + t;

    __shared__ __align__(16) uint32_t h1u[2][HD / 2];
    __shared__ float comb[512];
    __shared__ float ghs[G3], gis[G3];
    __shared__ float hfp[HD];
    __shared__ float inp[56];
    __shared__ float pf1[448];

    const float bi = bihd[t], bh = bhhd[t];

    if (t < 512)
        comb[t] = (t < 256) ? hfin[(size_t)n * HD + t]
                            : hfin[(size_t)(NSEQ + n) * HD + (t - 256)];
    if (t < 56) inp[t] = 0.0f;
    __syncthreads();

    float h_own = 0.0f;
    if (t < HD) {
        float acc = badj[t];
#pragma unroll 8
        for (int f = 0; f < 512; ++f) acc += wadjT[f * HD + t] * comb[f];
        h_own = acc;
        ((__half*)h1u[0])[t] = __float2half(acc);
        hfp[t] = acc;
    }
    __syncthreads();

    for (int step = 0; step < 6; ++step) {
        const uint32_t* hb = h1u[step & 1];
        float a0 = 0.f, a1 = 0.f;
#pragma unroll 8
        for (int q = 0; q < 32; ++q) {
            const uint4 w = wq[q * G3];
            const uint4 hp = *(const uint4*)&hb[4 * q];
            a0 = fdot2u(w.x, hp.x, a0); a1 = fdot2u(w.y, hp.y, a1);
            a0 = fdot2u(w.z, hp.z, a0); a1 = fdot2u(w.w, hp.w, a1);
        }
        float ai = bi;
#pragma unroll 8
        for (int v = 0; v < 56; ++v) ai += wihdT[v * G3 + t] * inp[v];
        ghs[t] = a0 + a1 + bh;
        gis[t] = ai;
        __syncthreads();
        if (t < HD) {
            const float r  = sigmf(gis[t] + ghs[t]);
            const float z  = sigmf(gis[HD + t] + ghs[HD + t]);
            const float nn = tanhf(gis[2 * HD + t] + r * ghs[2 * HD + t]);
            const float hnew = (1.0f - z) * nn + z * h_own;
            h_own = hnew;
            ((__half*)h1u[(step + 1) & 1])[t] = __float2half(hnew);
            hfp[t] = hnew;
        }
        __syncthreads();
        if (t < 448) {
            const int v = t >> 3, g = t & 7;
            float o = 0.f;
#pragma unroll
            for (int k2 = 0; k2 < 32; ++k2)
                o += wfc1T[(g * 32 + k2) * 56 + v] * hfp[g * 32 + k2];
            pf1[t] = o;
        }
        __syncthreads();
        if (t < 56) {
            float o = bfc1[t];
#pragma unroll
            for (int g = 0; g < 8; ++g) o += pf1[t * 8 + g];
            out[(size_t)n * 336 + step * 56 + t] = o;
            inp[t] = o;
        }
        __syncthreads();
    }
}

// ---------------------------------------------------------------------------
extern "C" void kernel_launch(void* const* d_in, const int* in_sizes, int n_in,
                              void* d_out, int out_size, void* d_ws, size_t ws_size,
                              hipStream_t stream)
{
    const float* x      = (const float*)d_in[0];
    const float* wih1f  = (const float*)d_in[1];
    const float* whh1f  = (const float*)d_in[2];
    const float* bih1f  = (const float*)d_in[3];
    const float* bhh1f  = (const float*)d_in[4];
    const float* wih1b  = (const float*)d_in[5];
    const float* whh1b  = (const float*)d_in[6];
    const float* bih1b  = (const float*)d_in[7];
    const float* bhh1b  = (const float*)d_in[8];
    const float* wih2f  = (const float*)d_in[9];
    const float* whh2f  = (const float*)d_in[10];
    const float* bih2f  = (const float*)d_in[11];
    const float* bhh2f  = (const float*)d_in[12];
    const float* wih2b  = (const float*)d_in[13];
    const float* whh2b  = (const float*)d_in[14];
    const float* bih2b  = (const float*)d_in[15];
    const float* bhh2b  = (const float*)d_in[16];
    const float* wihd   = (const float*)d_in[17];
    const float* whhd   = (const float*)d_in[18];
    const float* bihd   = (const float*)d_in[19];
    const float* bhhd   = (const float*)d_in[20];
    const float* wfc1   = (const float*)d_in[21];
    const float* bfc1   = (const float*)d_in[22];
    const float* wadj   = (const float*)d_in[23];
    const float* badj   = (const float*)d_in[24];

    float* ws = (float*)d_ws;
    __half*   seqg_h  = (__half*)(ws + 0);           // 786432 f16
    float*    gi_f    = ws + 393216;                 // 3145728
    float*    gi_b    = ws + 3538944;                // 3145728
    __half*   y1h     = (__half*)(ws + 6684672);     // 2097152 f16
    float*    hfin    = ws + 7733248;                // 32768
    uint32_t* wt1f    = (uint32_t*)(ws + 7782400);   // 98304 each
    uint32_t* wt1b    = (uint32_t*)(ws + 7880704);
    uint32_t* wt2f    = (uint32_t*)(ws + 7979008);
    uint32_t* wt2b    = (uint32_t*)(ws + 8077312);
    uint32_t* wtd     = (uint32_t*)(ws + 8175616);
    __half*   wih1f_h = (__half*)(ws + 8273920);     // 147456 f16
    __half*   wih1b_h = (__half*)(ws + 8347648);
    __half*   wih2f_h = (__half*)(ws + 8421376);     // 393216 f16
    __half*   wih2b_h = (__half*)(ws + 8617984);
    float*    wihdT   = ws + 8814592;                // 43008
    float*    wadjT   = ws + 8857600;                // 131072
    float*    wfc1T   = ws + 8988672;                // 14336

    // dynamic-LDS opt-in for gemm<512> (66560B > 64KB default)
    const int g192_lds = 64 * (192 + 8) * 2;         // 25600 B
    const int g512_lds = 64 * (512 + 8) * 2;         // 66560 B
    hipFuncSetAttribute((const void*)gemm_mfma<512>,
                        hipFuncAttributeMaxDynamicSharedMemorySize, g512_lds);

    prep_all<<<5344, 256, 0, stream>>>(
        whh1f, whh1b, whh2f, whh2b, whhd,
        wt1f, wt1b, wt2f, wt2b, wtd,
        wih1f, wih1b, wih2f, wih2b,
        wih1f_h, wih1b_h, wih2f_h, wih2b_h,
        wihd, wadj, wfc1, wihdT, wadjT, wfc1T,
        x, seqg_h);

    // layer 1
    gemm_mfma<192><<<dim3(64, 12, 2), 256, g192_lds, stream>>>(
        seqg_h, wih1f_h, wih1b_h, bih1f, bih1b, gi_f, gi_b);
    gru_scan<<<128, 512, 0, stream>>>(
        gi_f, gi_b, wt1f, wt1b, bhh1f, bhh1b, y1h, hfin);

    // layer 2 (gi buffers reused; scan2's y1h writes are dead but harmless)
    gemm_mfma<512><<<dim3(64, 12, 2), 256, g512_lds, stream>>>(
        y1h, wih2f_h, wih2b_h, bih2f, bih2b, gi_f, gi_b);
    gru_scan<<<128, 512, 0, stream>>>(
        gi_f, gi_b, wt2f, wt2b, bhh2f, bhh2b, y1h, hfin);

    // decoder head (adj fused)
    decoder_kernel<<<64, 768, 0, stream>>>(
        hfin, wadjT, badj, wtd, wihdT, bihd, bhhd, wfc1T, bfc1,
        (float*)d_out);
}